// Round 8
// baseline (97.696 us; speedup 1.0000x reference)
//
#include <hip/hip_runtime.h>
#include <hip/hip_bf16.h>
#include <stdint.h>

// Problem constants
#define KD 2304    // K = C*3*3
#define LD 3136    // L = 56*56
#define ND 256     // output channels
#define MD 25088   // B*L
#define CD 256     // input channels
#define PITCH 64   // padded row pitch (floats)
#define PROWS 58
#define PLANE (PROWS * PITCH)   // 3712 floats per padded channel plane

typedef __bf16 bf16x8 __attribute__((ext_vector_type(8)));
typedef float f32x4 __attribute__((ext_vector_type(4)));
typedef float f32x4u __attribute__((ext_vector_type(4), aligned(4)));

__device__ __forceinline__ void gload_lds16(const void* g, void* l) {
  __builtin_amdgcn_global_load_lds(
      (const __attribute__((address_space(1))) unsigned int*)g,
      (__attribute__((address_space(3))) unsigned int*)l, 16, 0, 0);
}

// ---------------- Phase -1: zero-pad x into [B*C][58][PITCH=64] ----------------
__global__ __launch_bounds__(256) void pad_kernel(
    const float* __restrict__ x, float* __restrict__ xpad) {
  const int plane = blockIdx.x;
  const float* src = x + (size_t)plane * LD;
  float* dst = xpad + (size_t)plane * PLANE;
  const int cc4 = (threadIdx.x & 15) * 4;
  const int r0 = threadIdx.x >> 4;
#pragma unroll
  for (int p = 0; p < 4; ++p) {
    const int r = r0 + p * 16;
    if (r >= PROWS) continue;
    f32x4 o = {0.f, 0.f, 0.f, 0.f};
    if (r >= 1 && r <= 56) {
      const float* srow = src + (r - 1) * 56;
      if (cc4 == 0) {
        f32x4u v = *(const f32x4u*)(srow);
        o[1] = v[0]; o[2] = v[1]; o[3] = v[2];
      } else if (cc4 <= 52) {
        o = *(const f32x4u*)(srow + cc4 - 1);
      } else if (cc4 == 56) {
        f32x4u v = *(const f32x4u*)(srow + 52);
        o[0] = v[3];
      }
    }
    *(f32x4*)(dst + r * PITCH + cc4) = o;
  }
}

// ---------------- Phase 0: weight fake-quant -> wqT [N][K] bf16 ----------------
__global__ __launch_bounds__(256) void quant_w_kernel(
    const float* __restrict__ w, __hip_bfloat16* __restrict__ wqT) {
  const int gk = blockIdx.x % 72;
  const int gn = blockIdx.x / 72;
  const int n = gn * 32 + (threadIdx.x >> 3);
  const int k = gk * 32 + (threadIdx.x & 7) * 4;
  const float4 v = *(const float4*)(w + (size_t)n * KD + k);
  float a = fmaxf(fmaxf(fabsf(v.x), fabsf(v.y)), fmaxf(fabsf(v.z), fabsf(v.w)));
#pragma unroll
  for (int m = 1; m <= 32; m <<= 1) a = fmaxf(a, __shfl_xor(a, m, 64));
  __shared__ float red[4];
  if ((threadIdx.x & 63) == 0) red[threadIdx.x >> 6] = a;
  __syncthreads();
  const float mx = fmaxf(fmaxf(red[0], red[1]), fmaxf(red[2], red[3]));
  const float r63 = (mx == 0.f) ? 0.f : 63.f / mx;
  const float scale = mx * (1.f / 63.f);
  ushort4 o;
  o.x = __builtin_bit_cast(unsigned short, __float2bfloat16(rintf(v.x * r63) * scale));
  o.y = __builtin_bit_cast(unsigned short, __float2bfloat16(rintf(v.y * r63) * scale));
  o.z = __builtin_bit_cast(unsigned short, __float2bfloat16(rintf(v.z * r63) * scale));
  o.w = __builtin_bit_cast(unsigned short, __float2bfloat16(rintf(v.w * r63) * scale));
  *(ushort4*)((unsigned short*)wqT + (size_t)n * KD + k) = o;
}

// ---- UNIFORM window prefetch: always 5 channels x 3 rows (phase-independent) ----
__device__ __forceinline__ void qload_u(const float* __restrict__ pb, int p0,
                                        int c0, f32x4u (&win)[5][3]) {
#pragma unroll
  for (int dc = 0; dc < 5; ++dc) {
    const int cdc = (c0 + dc > 255) ? 255 : c0 + dc;
    const float* cp = pb + p0 + cdc * PLANE;
#pragma unroll
    for (int di = 0; di < 3; ++di)
      win[dc][di] = *(const f32x4u*)(cp + di * PITCH);
  }
}

// ---- finish quant: tree-max, rcp, quant, cvt_pk to bf16, swizzled LDS write ----
// as_row = As + lane*256; swizzle: 16B unit u of row r holds logical unit u^(r&15)
template <int KP0>
__device__ __forceinline__ void qfinish(const f32x4u (&win)[5][3],
                                        char* as_row, unsigned cbase, unsigned swz) {
  float v[32];
#pragma unroll
  for (int t = 0; t < 32; ++t) {
    const int idx = KP0 + t;
    v[t] = win[idx / 9][(idx % 9) / 3][(idx % 9) % 3];
  }
  float m16[16];
#pragma unroll
  for (int t = 0; t < 16; ++t)
    m16[t] = fmaxf(__builtin_fabsf(v[2 * t]), __builtin_fabsf(v[2 * t + 1]));
#pragma unroll
  for (int t = 0; t < 8; ++t) m16[t] = fmaxf(m16[t], m16[t + 8]);
#pragma unroll
  for (int t = 0; t < 4; ++t) m16[t] = fmaxf(m16[t], m16[t + 4]);
  const float mx = fmaxf(fmaxf(m16[0], m16[1]), fmaxf(m16[2], m16[3]));
  float r63 = 63.f * __builtin_amdgcn_rcpf(mx);
  r63 = (mx == 0.f) ? 0.f : r63;
  const float scale = mx * (1.f / 63.f);
  unsigned pk[16];
#pragma unroll
  for (int t = 0; t < 16; ++t) {
    const float a = rintf(v[2 * t] * r63) * scale;
    const float b = rintf(v[2 * t + 1] * r63) * scale;
    unsigned d;
    asm("v_cvt_pk_bf16_f32 %0, %1, %2" : "=v"(d) : "v"(a), "v"(b));
    pk[t] = d;
  }
#pragma unroll
  for (int s = 0; s < 4; ++s) {
    uint4 o = {pk[4 * s], pk[4 * s + 1], pk[4 * s + 2], pk[4 * s + 3]};
    *(uint4*)(as_row + ((cbase + (unsigned)(s * 16)) ^ swz)) = o;
  }
}

// ---- stage 128x128 wqT tile (32KB) via global_load_lds, pre-swizzled source ----
// LDS rows 256B; unit u of row r holds source unit u^(r&15). 8 chunks/wave.
__device__ __forceinline__ void stage_ns(const unsigned short* __restrict__ wsrc,
                                         int k0, int lane, int w, char* Ns) {
  const int hv4 = lane >> 4;
#pragma unroll
  for (int sg = 0; sg < 8; ++sg) {
    const int c = w * 8 + sg;                  // 1KB chunk (4 rows of 256B)
    const int rowN = c * 4 + hv4;
    const int u = (lane & 15) ^ (rowN & 15);
    gload_lds16(wsrc + (size_t)rowN * KD + k0 + u * 8,
                Ns + c * 1024 + lane * 16);
  }
}

// ---- MFMA: wave tile 64n x 32m, BK=128 (4 k-slices) ----
__device__ __forceinline__ void mfma_phase(const char* As, const char* Ns,
                                           f32x4 (&acc)[4][2], int wn, int wm,
                                           int lq, int hv) {
  const unsigned swq = (unsigned)(lq << 4);
#pragma unroll
  for (int kk = 0; kk < 4; ++kk) {
    const unsigned ko = (unsigned)(kk * 64 + hv * 16);
    bf16x8 af[4], bfr[2];
#pragma unroll
    for (int ifr = 0; ifr < 4; ++ifr) {
      const unsigned rn = (unsigned)(wn * 64 + ifr * 16 + lq);
      af[ifr] = *(const bf16x8*)(Ns + rn * 256u + (ko ^ swq));
    }
#pragma unroll
    for (int jfr = 0; jfr < 2; ++jfr) {
      const unsigned rm = (unsigned)(wm * 32 + jfr * 16 + lq);
      bfr[jfr] = *(const bf16x8*)(As + rm * 256u + (ko ^ swq));
    }
#pragma unroll
    for (int ifr = 0; ifr < 4; ++ifr)
#pragma unroll
      for (int jfr = 0; jfr < 2; ++jfr)
        acc[ifr][jfr] = __builtin_amdgcn_mfma_f32_16x16x32_bf16(
            af[ifr], bfr[jfr], acc[ifr][jfr], 0, 0, 0);
  }
}

// ---------------- Fused: unfold+quant-A + B-stage + GEMM + bias ----------------
// BM=64, BN=128, BK=128, 4 waves, 48KB LDS -> 3 blocks/CU, grid 784 (3.06/CU).
// Per step: stage Ns (8 async gload_lds/wave) | qfinish(win)->As | qload next
// win (15 loads stay in flight across barrier, vmcnt(15)) -> MFMA -> barrier.
__global__ __launch_bounds__(256, 3) void fused_gemm_kernel(
    const float* __restrict__ xpad, const __hip_bfloat16* __restrict__ wqT,
    const float* __restrict__ bias, float* __restrict__ out) {
  __shared__ char As[64 * 256];     // 16KB, swizzled
  __shared__ char Ns[128 * 256];    // 32KB, swizzled via source
  const int tid = threadIdx.x;
  const int lane = tid & 63;
  const int w = __builtin_amdgcn_readfirstlane(tid >> 6);

  const int bid = blockIdx.x;                    // 0..783
  const int xcd = bid & 7;
  const int idx = bid >> 3;                      // 0..97
  const int mt = xcd * 49 + (idx >> 1);          // image xcd -> XCD xcd (L2 local)
  const int nt = idx & 1;
  const int m0 = mt * 64;
  const int n1 = nt * 128;

  const int b = m0 / LD;                         // uniform (3136 % 64 == 0)
  const int l = m0 - b * LD + lane;
  const int i = l / 56;
  const int j = l - i * 56;
  const float* pb = xpad + (size_t)b * CD * PLANE;
  const int p0 = i * PITCH + j;
  char* as_row = As + lane * 256;
  const unsigned swz = (unsigned)((lane & 15) << 4);
  const unsigned cbase = (unsigned)(w * 64);
  const unsigned short* wsrc = (const unsigned short*)wqT + (size_t)n1 * KD;

  const int lq = lane & 15, hv = lane >> 4;
  const int wn = w & 1, wm = w >> 1;

  f32x4 acc[4][2] = {};
  f32x4u win[5][3];

  // granule of wave w at step R: k = 32w + 128R; phase = k % 9; c0 = k / 9
  int kbase = 32 * w;
  int ph = (32 * w) % 9;
  qload_u(pb, p0, kbase / 9, win);   // prologue prefetch (step 0)

  for (int R = 0; R < 18; ++R) {
    stage_ns(wsrc, R * 128, lane, w, Ns);   // 8 async gload_lds -> Ns

    switch (ph) {                           // consume win -> As (wave-uniform)
      case 0: qfinish<0>(win, as_row, cbase, swz); break;
      case 1: qfinish<1>(win, as_row, cbase, swz); break;
      case 2: qfinish<2>(win, as_row, cbase, swz); break;
      case 3: qfinish<3>(win, as_row, cbase, swz); break;
      case 4: qfinish<4>(win, as_row, cbase, swz); break;
      case 5: qfinish<5>(win, as_row, cbase, swz); break;
      case 6: qfinish<6>(win, as_row, cbase, swz); break;
      default: qfinish<7>(win, as_row, cbase, swz); break;
      case 8: qfinish<8>(win, as_row, cbase, swz); break;
    }

    // prefetch next step's windows (dummy on last iter; clamp keeps in-bounds)
    kbase += 128;
    ph += 2; if (ph >= 9) ph -= 9;
    qload_u(pb, p0, kbase / 9, win);        // 15 loads stay in flight past barrier

    asm volatile("s_waitcnt vmcnt(15) lgkmcnt(0)\n\ts_barrier" ::: "memory");
    __builtin_amdgcn_sched_barrier(0);

    mfma_phase(As, Ns, acc, wn, wm, lq, hv);

    asm volatile("s_waitcnt lgkmcnt(0)\n\ts_barrier" ::: "memory");
    __builtin_amdgcn_sched_barrier(0);
  }

  // ---- Epilogue: D row = n = n1 + wn*64 + ifr*16 + hv*4 + comp, col = m ----
#pragma unroll
  for (int ifr = 0; ifr < 4; ++ifr) {
    const int nb = n1 + wn * 64 + ifr * 16 + hv * 4;
    const float4 b4 = *(const float4*)&bias[nb];
#pragma unroll
    for (int jfr = 0; jfr < 2; ++jfr) {
      const int m = m0 + wm * 32 + jfr * 16 + lq;
      const int ll = m - b * LD;
      float* op = out + ((size_t)b * ND + nb) * LD + ll;
      op[0]      = acc[ifr][jfr].x + b4.x;
      op[LD]     = acc[ifr][jfr].y + b4.y;
      op[2 * LD] = acc[ifr][jfr].z + b4.z;
      op[3 * LD] = acc[ifr][jfr].w + b4.w;
    }
  }
}

extern "C" void kernel_launch(void* const* d_in, const int* in_sizes, int n_in,
                              void* d_out, int out_size, void* d_ws, size_t ws_size,
                              hipStream_t stream) {
  const float* x = (const float*)d_in[0];
  const float* wgt = (const float*)d_in[1];
  const float* bias = (const float*)d_in[2];
  float* out = (float*)d_out;

  float* xpad = (float*)d_ws;                         // 8*256*3712*4 = 30,408,704 B
  __hip_bfloat16* wqT = (__hip_bfloat16*)((char*)d_ws + 30408704);  // 1,179,648 B

  pad_kernel<<<8 * CD, 256, 0, stream>>>(x, xpad);
  quant_w_kernel<<<576, 256, 0, stream>>>(wgt, wqT);
  fused_gemm_kernel<<<784, 256, 0, stream>>>(xpad, wqT, bias, out);
}